// Round 7
// baseline (297.890 us; speedup 1.0000x reference)
//
#include <hip/hip_runtime.h>
#include <hip/hip_bf16.h>
#include <cmath>

#define B_   2
#define S_   2048
#define D_   2048
#define H_   32
#define HKV_ 8
#define HD_  64
// G = H/HKV = 4

using bf16 = __hip_bfloat16;
typedef __bf16    bf16x8 __attribute__((ext_vector_type(8)));
typedef float     floatx4 __attribute__((ext_vector_type(4)));
typedef _Float16  half4 __attribute__((ext_vector_type(4)));
typedef __fp16    fp16x2 __attribute__((ext_vector_type(2)));

#if __has_builtin(__builtin_amdgcn_exp2f)
#define EXP2(x) __builtin_amdgcn_exp2f(x)
#else
#define EXP2(x) exp2f(x)
#endif

#define QSCALE 0.18033688011112042f   // 0.125 * log2(e)

__device__ inline void async16(const void* g, void* l) {
  __builtin_amdgcn_global_load_lds(
      (const __attribute__((address_space(1))) void*)g,
      (__attribute__((address_space(3))) void*)l, 16, 0, 0);
}

__device__ inline half4 pack4(float a, float b, float c, float d) {
  union { fp16x2 h2[2]; half4 h4; } u;
  u.h2[0] = __builtin_amdgcn_cvt_pkrtz(a, b);
  u.h2[1] = __builtin_amdgcn_cvt_pkrtz(c, d);
  return u.h4;
}

#define MFMA32B(a, b, c) __builtin_amdgcn_mfma_f32_16x16x32_bf16((a), (b), (c), 0, 0, 0)
#define MFMA16H(a, b, c) __builtin_amdgcn_mfma_f32_16x16x16f16((a), (b), (c), 0, 0, 0)

// ---------- fused fp32->bf16 conversion for all 5 tensors (wq pre-scaled) ---
__global__ void f2b_all(const float* __restrict__ x,  const float* __restrict__ wq,
                        const float* __restrict__ wk, const float* __restrict__ wv,
                        const float* __restrict__ wo,
                        bf16* __restrict__ xb,  bf16* __restrict__ wqb,
                        bf16* __restrict__ wkb, bf16* __restrict__ wvb,
                        bf16* __restrict__ wob) {
  const int i = blockIdx.x * blockDim.x + threadIdx.x;
  const float* src; bf16* dst; int off; float scale = 1.0f;
  if (i < 1048576)      { src = x;  dst = xb;  off = 0; }
  else if (i < 1572864) { src = wq; dst = wqb; off = 1048576; scale = QSCALE; }
  else if (i < 1703936) { src = wk; dst = wkb; off = 1572864; }
  else if (i < 1835008) { src = wv; dst = wvb; off = 1703936; }
  else                  { src = wo; dst = wob; off = 1835008; }
  const int j = i - off;
  float4 a  = ((const float4*)src)[2 * j];
  float4 b2 = ((const float4*)src)[2 * j + 1];
  alignas(16) bf16 t[8];
  t[0] = __float2bfloat16(a.x * scale);  t[1] = __float2bfloat16(a.y * scale);
  t[2] = __float2bfloat16(a.z * scale);  t[3] = __float2bfloat16(a.w * scale);
  t[4] = __float2bfloat16(b2.x * scale); t[5] = __float2bfloat16(b2.y * scale);
  t[6] = __float2bfloat16(b2.z * scale); t[7] = __float2bfloat16(b2.w * scale);
  ((uint4*)dst)[j] = *(const uint4*)t;
}

// -------------------- shared GEMM tile body: C = A * B^T + bias*bscale ------
// Double-buffered LDS prefetch: one barrier/iter, stage(k+1) overlaps compute(k).
// MODE 0: bf16 row-major (swapped MFMA -> packed 8B stores)
// MODE 1: f32 row-major  (swapped MFMA -> float4 stores)
// MODE 2: f16 V-tiled layout (original order -> packed 8B stores, j==r contig)
template <int MODE, typename OutT>
__device__ inline void gemm_body(const bf16* __restrict__ Ag, const bf16* __restrict__ Bg,
                                 const float* __restrict__ bias, float bscale,
                                 OutT* __restrict__ C, int Ncol, int K, int bm, int colb,
                                 bf16* As, bf16* Bs) {
  const int tid  = threadIdx.x;
  const int wid  = tid >> 6, lane = tid & 63;
  const int lm   = lane & 15, quad = lane >> 4;
  const int wm   = (wid >> 1) * 64, wn = (wid & 1) * 64;

  floatx4 acc[4][4] = {};

  const int l0 = tid * 8;
  const int r0 = l0 >> 5, c0 = l0 & 31;
  const int r1 = r0 + 64;

  auto stage = [&](int k0, int buf) {
    const int o = buf * 4096;
    async16(Ag + (size_t)r0 * K + k0 + c0, &As[o + l0]);
    async16(Ag + (size_t)r1 * K + k0 + c0, &As[o + l0 + 2048]);
    async16(Bg + (size_t)r0 * K + k0 + c0, &Bs[o + l0]);
    async16(Bg + (size_t)r1 * K + k0 + c0, &Bs[o + l0 + 2048]);
  };

  stage(0, 0);

  for (int k0 = 0; k0 < K; k0 += 32) {
    const int cur = (k0 >> 5) & 1;
    asm volatile("s_waitcnt vmcnt(0)" ::: "memory");
    __syncthreads();
    if (k0 + 32 < K) stage(k0 + 32, cur ^ 1);

    const bf16* Ab = &As[cur * 4096];
    const bf16* Bb = &Bs[cur * 4096];
    bf16x8 aF[4], bF[4];
#pragma unroll
    for (int mi = 0; mi < 4; ++mi)
      aF[mi] = *(const bf16x8*)&Ab[(wm + mi * 16 + lm) * 32 + quad * 8];
#pragma unroll
    for (int ni = 0; ni < 4; ++ni)
      bF[ni] = *(const bf16x8*)&Bb[(wn + ni * 16 + lm) * 32 + quad * 8];
#pragma unroll
    for (int mi = 0; mi < 4; ++mi)
#pragma unroll
      for (int ni = 0; ni < 4; ++ni) {
        if constexpr (MODE == 2)
          acc[mi][ni] = MFMA32B(aF[mi], bF[ni], acc[mi][ni]);
        else
          acc[mi][ni] = MFMA32B(bF[ni], aF[mi], acc[mi][ni]);  // swapped: D^T
      }
  }

  if constexpr (MODE != 2) {
    // swapped layout: lane holds row m = ..+lm, cols n = col0..col0+3
#pragma unroll
    for (int mi = 0; mi < 4; ++mi) {
      const int row = bm * 128 + wm + mi * 16 + lm;
#pragma unroll
      for (int ni = 0; ni < 4; ++ni) {
        const int col0 = colb + wn + ni * 16 + quad * 4;
        float4 bv4 = *(const float4*)&bias[col0];
        if constexpr (MODE == 0) {
          alignas(8) bf16 t4[4];
#pragma unroll
          for (int r = 0; r < 4; ++r)
            t4[r] = __float2bfloat16(acc[mi][ni][r] + ((const float*)&bv4)[r] * bscale);
          *(uint2*)&((bf16*)C)[(size_t)row * Ncol + col0] = *(const uint2*)t4;
        } else {
          float4 o4;
          o4.x = acc[mi][ni][0] + bv4.x; o4.y = acc[mi][ni][1] + bv4.y;
          o4.z = acc[mi][ni][2] + bv4.z; o4.w = acc[mi][ni][3] + bv4.w;
          *(float4*)&((float*)C)[(size_t)row * Ncol + col0] = o4;
        }
      }
    }
  } else {
    // V tiled: per (b,kvh), 32 tiles of 64kv x 64hd, [kc][nh][qd][lmw][j];
    // lane's 4 r-values are j=0..3 contiguous.
#pragma unroll
    for (int mi = 0; mi < 4; ++mi) {
      const int rowg = bm * 128 + wm + mi * 16 + quad * 4;   // %4 == 0
      const int b    = rowg >> 11, s = rowg & 2047;
      const int tile = s >> 6, kvin = s & 63;
      const int kc = kvin >> 4, qd = (kvin >> 2) & 3;
#pragma unroll
      for (int ni = 0; ni < 4; ++ni) {
        const int col = colb + wn + ni * 16 + lm;            // 0..511
        const float bv = bias[col];
        const int kvh = col >> 6, hd = col & 63;
        const int nh = hd >> 4, lmw = hd & 15;
        const size_t base = ((size_t)((b * 8 + kvh) * 32 + tile) << 12) +
                            (((kc * 4 + nh) * 4 + qd) << 6) + (lmw << 2);
        alignas(8) _Float16 t4[4];
#pragma unroll
        for (int r = 0; r < 4; ++r)
          t4[r] = (_Float16)(acc[mi][ni][r] + bv);
        *(uint2*)&((_Float16*)C)[base] = *(const uint2*)t4;
      }
    }
  }
}

// Fused QKV projection: grid.x 0..23 -> Q(16, pre-scaled) | K(4) | V(4, tiled f16)
__global__ __launch_bounds__(256, 3)
void gemm_qkv(const bf16* __restrict__ xb,
              const bf16* __restrict__ wq, const bf16* __restrict__ wk,
              const bf16* __restrict__ wv,
              const float* __restrict__ bq, const float* __restrict__ bk,
              const float* __restrict__ bv,
              bf16* __restrict__ Qo, bf16* __restrict__ Ko, _Float16* __restrict__ VG) {
  __shared__ bf16 As[2 * 128 * 32];
  __shared__ bf16 Bs[2 * 128 * 32];
  const int bn = blockIdx.x, bm = blockIdx.y;
  const int K = D_;
  if (bn < 16) {
    gemm_body<0, bf16>(xb + (size_t)bm * 128 * K, wq + (size_t)(bn * 128) * K, bq, QSCALE,
                       Qo, H_ * HD_, K, bm, bn * 128, As, Bs);
  } else if (bn < 20) {
    gemm_body<0, bf16>(xb + (size_t)bm * 128 * K, wk + (size_t)((bn - 16) * 128) * K, bk, 1.0f,
                       Ko, HKV_ * HD_, K, bm, (bn - 16) * 128, As, Bs);
  } else {
    gemm_body<2, _Float16>(xb + (size_t)bm * 128 * K, wv + (size_t)((bn - 20) * 128) * K, bv, 1.0f,
                           VG, HKV_ * HD_, K, bm, (bn - 20) * 128, As, Bs);
  }
}

// Plain GEMM (O-projection): C fp32 = A * B^T + bias
__global__ __launch_bounds__(256, 3)
void gemm_o(const bf16* __restrict__ A, const bf16* __restrict__ Bm,
            const float* __restrict__ bias, float* __restrict__ C,
            int Ncol, int K) {
  __shared__ bf16 As[2 * 128 * 32];
  __shared__ bf16 Bs[2 * 128 * 32];
  const int bn = blockIdx.x, bm = blockIdx.y;
  gemm_body<1, float>(A + (size_t)bm * 128 * K, Bm + (size_t)bn * 128 * K, bias, 1.0f,
                      C, Ncol, K, bm, bn * 128, As, Bs);
}

// -------------------- causal GQA flash attention, v6 ------------------------
// Block = (pair, b, kvh): 4 waves = 4 heads of one GQA group sharing K/V LDS.
// Each wave owns two 16-row q-tiles (hi=127-pair, lo=pair), interleaved kv-loop.
// P register-resident; l-sum via single ones-MFMA on VALU-presummed P chunks.
__global__ __launch_bounds__(256, 4)
void attn_kernel(const bf16* __restrict__ Q, const bf16* __restrict__ K,
                 const _Float16* __restrict__ VG, bf16* __restrict__ O) {
  const int tid = threadIdx.x;
  const int wid = tid >> 6, lane = tid & 63;
  const int lm = lane & 15, quad = lane >> 4;

  // XCD-aware swizzle: group (b,kvh) pinned to one XCD (2 groups/XCD)
  const int n   = blockIdx.y * 64 + blockIdx.x;   // grid (64, 16)
  const int x3  = n & 7, b1 = (n >> 3) & 1;
  const int pair = n >> 4;                        // 0..63
  const int grp  = x3 * 2 + b1;                   // 0..15 == b*8 + kvh
  const int b    = grp >> 3, kvh = grp & 7;
  const int head = kvh * 4 + wid;

  const int hi = 127 - pair, lo = pair;
  const int nt_hi = (hi >> 2) + 1;                // 17..32
  const int nt_lo = (lo >> 2) + 1;

  __shared__ bf16     Ks[2 * 64 * 64];   // [buf][hd-half][kv][32]
  __shared__ _Float16 Vs[2 * 64 * 64];   // [buf][tiled 4096]

  const int tb[2] = {hi * 16, lo * 16};

  bf16x8 qf[2][2];
#pragma unroll
  for (int tt = 0; tt < 2; ++tt) {
    const size_t qg = ((size_t)(b * S_ + tb[tt] + lm)) * (H_ * HD_) + head * HD_;
#pragma unroll
    for (int kf = 0; kf < 2; ++kf)
      qf[tt][kf] = *(const bf16x8*)&Q[qg + kf * 32 + quad * 8];
  }

  half4 onesh;
#pragma unroll
  for (int j = 0; j < 4; ++j) onesh[j] = (_Float16)1.0f;

  floatx4 o_acc[2][4] = {};
  floatx4 lacc[2] = {};

  const int tr = tid >> 2;          // staging row 0..63
  const int tc = (tid & 3) * 8;

  auto stage = [&](int t, int buf) {
#pragma unroll
    for (int c = 0; c < 2; ++c) {
      async16(&K[(size_t)(b * S_ + t * 64 + tr) * (HKV_ * HD_) + kvh * HD_ + c * 32 + tc],
              &Ks[buf * 4096 + c * 2048 + tid * 8]);
      async16(&VG[((size_t)(grp * 32 + t) << 12) + c * 2048 + tid * 8],
              &Vs[buf * 4096 + c * 2048 + tid * 8]);
    }
  };

  stage(0, 0);

  for (int t = 0; t < nt_hi; ++t) {
    const int cur = t & 1;
    asm volatile("s_waitcnt vmcnt(0)" ::: "memory");
    __syncthreads();
    if (t + 1 < nt_hi) stage(t + 1, cur ^ 1);

    const bf16*     Kb = &Ks[cur * 4096];
    const _Float16* Vb = &Vs[cur * 4096];
    const int t0 = t * 64;
    const int nact = (t < nt_lo) ? 2 : 1;

    int kcmax[2], kcross[2];
#pragma unroll
    for (int tt = 0; tt < 2; ++tt) {
      const int rel = tb[tt] + 15 - t0;
      kcmax[tt]  = (tt < nact) ? ((rel >> 4) >= 3 ? 4 : (rel >> 4) + 1) : 0;
      kcross[tt] = rel >> 4;
    }

    half4 pb[2][4];
#pragma unroll
    for (int kc = 0; kc < 4; ++kc) {
      if (kc >= kcmax[0]) break;   // kcmax[0] >= kcmax[1] always
      bf16x8 kb0 = *(const bf16x8*)&Kb[(kc * 16 + lm) * 32 + quad * 8];
      bf16x8 kb1 = *(const bf16x8*)&Kb[2048 + (kc * 16 + lm) * 32 + quad * 8];
#pragma unroll
      for (int tt = 0; tt < 2; ++tt) {
        if (kc >= kcmax[tt]) continue;
        floatx4 sT = {};
        sT = MFMA32B(kb0, qf[tt][0], sT);
        sT = MFMA32B(kb1, qf[tt][1], sT);
        float p[4];
        if (kc == kcross[tt]) {
          const int qrel = tb[tt] + lm - t0;   // q - t0
#pragma unroll
          for (int r = 0; r < 4; ++r)
            p[r] = (kc * 16 + quad * 4 + r > qrel) ? 0.f : EXP2(sT[r]);
        } else {
#pragma unroll
          for (int r = 0; r < 4; ++r) p[r] = EXP2(sT[r]);
        }
        pb[tt][kc] = pack4(p[0], p[1], p[2], p[3]);
      }
    }

    // row sums: presum chunks in f16 VALU, one ones-MFMA per tile
#pragma unroll
    for (int tt = 0; tt < 2; ++tt) {
      if (kcmax[tt] == 0) continue;
      half4 ps = pb[tt][0];
      if (kcmax[tt] > 1) ps += pb[tt][1];
      if (kcmax[tt] > 2) ps += pb[tt][2];
      if (kcmax[tt] > 3) ps += pb[tt][3];
      lacc[tt] = MFMA16H(onesh, ps, lacc[tt]);
    }

    // O^T += V^T * P^T
#pragma unroll
    for (int kc = 0; kc < 4; ++kc) {
      if (kc >= kcmax[0]) break;
#pragma unroll
      for (int nh = 0; nh < 4; ++nh) {
        half4 va = *(const half4*)&Vb[((kc * 4 + nh) * 4 + quad) * 64 + lm * 4];
#pragma unroll
        for (int tt = 0; tt < 2; ++tt)
          if (kc < kcmax[tt]) o_acc[tt][nh] = MFMA16H(va, pb[tt][kc], o_acc[tt][nh]);
      }
    }
  }

#pragma unroll
  for (int tt = 0; tt < 2; ++tt) {
    const float rl = 1.f / lacc[tt][0];
    const size_t rowg = (size_t)(b * S_ + tb[tt] + lm);
#pragma unroll
    for (int nh = 0; nh < 4; ++nh) {
      alignas(8) bf16 tmp[4];
#pragma unroll
      for (int r = 0; r < 4; ++r)
        tmp[r] = __float2bfloat16(o_acc[tt][nh][r] * rl);
      *(uint2*)&O[rowg * (H_ * HD_) + head * HD_ + nh * 16 + quad * 4] = *(uint2*)tmp;
    }
  }
}

// ---------------------------------------------------------------------------
extern "C" void kernel_launch(void* const* d_in, const int* in_sizes, int n_in,
                              void* d_out, int out_size, void* d_ws, size_t ws_size,
                              hipStream_t stream) {
  (void)in_sizes; (void)n_in; (void)out_size; (void)ws_size;
  const float* x  = (const float*)d_in[0];
  const float* wq = (const float*)d_in[1];
  const float* bq = (const float*)d_in[2];
  const float* wk = (const float*)d_in[3];
  const float* bk = (const float*)d_in[4];
  const float* wv = (const float*)d_in[5];
  const float* bv = (const float*)d_in[6];
  const float* wo = (const float*)d_in[7];
  const float* bo = (const float*)d_in[8];
  float* out = (float*)d_out;

  const int M = B_ * S_;        // 4096
  const int E = H_ * HD_;       // 2048
  const int EKV = HKV_ * HD_;   // 512

  char* ws = (char*)d_ws;
  size_t off = 0;
  auto alloc = [&](size_t bytes) {
    char* p = ws + off;
    off += (bytes + 255) & ~(size_t)255;
    return p;
  };
  bf16* xb  = (bf16*)alloc((size_t)M * D_ * 2);
  bf16* wqb = (bf16*)alloc((size_t)E * D_ * 2);
  bf16* wkb = (bf16*)alloc((size_t)EKV * D_ * 2);
  bf16* wvb = (bf16*)alloc((size_t)EKV * D_ * 2);
  bf16* wob = (bf16*)alloc((size_t)D_ * E * 2);
  bf16* Qb  = (bf16*)alloc((size_t)M * E * 2);
  bf16* Kb  = (bf16*)alloc((size_t)M * EKV * 2);
  _Float16* VG = (_Float16*)alloc((size_t)M * EKV * 2);  // tiled V, f16
  bf16* Ob  = (bf16*)alloc((size_t)M * E * 2);

  f2b_all<<<9216, 256, 0, stream>>>(x, wq, wk, wv, wo, xb, wqb, wkb, wvb, wob);

  gemm_qkv<<<dim3(24, M / 128), 256, 0, stream>>>(xb, wqb, wkb, wvb, bq, bk, bv,
                                                  Qb, Kb, VG);

  attn_kernel<<<dim3(64, 16), 256, 0, stream>>>(Qb, Kb, VG, Ob);

  gemm_o<<<dim3(D_ / 128, M / 128), 256, 0, stream>>>(Ob, wob, bo, out, D_, D_);
}